// Round 6
// baseline (820.015 us; speedup 1.0000x reference)
//
#include <hip/hip_runtime.h>

#define N_NODES 50000
#define N_EDGES 1600000
#define FX 128
#define FE 8
#define FIN 136          // FX + FE
#define NPAD 50048       // pad rows so 64-row GEMM tiles can over-read safely
#define NB_SCAN 196      // ceil(N_NODES / 256)
#define NXCD 8
#define NPC 6250         // nodes per XCD class (N_NODES / NXCD)
#define FCHUNK 2048      // edges per chunk in fill
#define NCHUNK ((N_EDGES + FCHUNK - 1) / FCHUNK)   // 782
#define CSLAB ((size_t)NPAD * 32)                  // elems per feature-chunk slab

typedef short short8v __attribute__((ext_vector_type(8)));
typedef float float4v __attribute__((ext_vector_type(4)));

__device__ inline float bf2f(unsigned short h) {
    return __uint_as_float((unsigned)h << 16);
}
__device__ inline unsigned short f2bf(float f) {   // round-to-nearest-even
    unsigned u = __float_as_uint(f);
    u = (u + 0x7FFF + ((u >> 16) & 1)) >> 16;
    return (unsigned short)u;
}

// ---------------------------------------------------------------- CSR build (y = branch)
__global__ void hist_kernel(const int* __restrict__ ei0, const int* __restrict__ ei1,
                            int* __restrict__ deg0, int* __restrict__ deg1) {
    const int* ei = blockIdx.y ? ei1 : ei0;
    int* deg      = blockIdx.y ? deg1 : deg0;
    int e = blockIdx.x * 256 + threadIdx.x;
    if (e >= N_EDGES) return;
    atomicAdd(&deg[__builtin_nontemporal_load(&ei[N_EDGES + e])], 1);
}

__global__ void scan1_kernel(const int* __restrict__ deg0, const int* __restrict__ deg1,
                             int* __restrict__ p0, int* __restrict__ p1) {
    const int* deg = blockIdx.y ? deg1 : deg0;
    int* partial   = blockIdx.y ? p1 : p0;
    __shared__ int red[256];
    int i = blockIdx.x * 256 + threadIdx.x;
    red[threadIdx.x] = (i < N_NODES) ? deg[i] : 0;
    __syncthreads();
    for (int off = 128; off > 0; off >>= 1) {
        if (threadIdx.x < off) red[threadIdx.x] += red[threadIdx.x + off];
        __syncthreads();
    }
    if (threadIdx.x == 0) partial[blockIdx.x] = red[0];
}

__global__ void scan2_kernel(const int* __restrict__ p0, const int* __restrict__ p1,
                             int* __restrict__ base0, int* __restrict__ base1,
                             int* __restrict__ rp0, int* __restrict__ rp1) {
    const int* partial = blockIdx.y ? p1 : p0;
    int* base          = blockIdx.y ? base1 : base0;
    int* row_ptr       = blockIdx.y ? rp1 : rp0;
    __shared__ int s[256];
    int t = threadIdx.x;
    int v = (t < NB_SCAN) ? partial[t] : 0;
    s[t] = v;
    __syncthreads();
    for (int off = 1; off < 256; off <<= 1) {
        int u = (t >= off) ? s[t - off] : 0;
        __syncthreads();
        s[t] += u;
        __syncthreads();
    }
    if (t < NB_SCAN) base[t] = s[t] - v;
    if (t == 255) row_ptr[N_NODES] = s[255];
}

__global__ void scan3_kernel(const int* __restrict__ deg0, const int* __restrict__ deg1,
                             const int* __restrict__ base0, const int* __restrict__ base1,
                             int* __restrict__ rp0, int* __restrict__ rp1,
                             int* __restrict__ cur0, int* __restrict__ cur1) {
    const int* deg  = blockIdx.y ? deg1 : deg0;
    const int* base = blockIdx.y ? base1 : base0;
    int* row_ptr    = blockIdx.y ? rp1 : rp0;
    int* cursor     = blockIdx.y ? cur1 : cur0;
    __shared__ int s[256];
    int i = blockIdx.x * 256 + threadIdx.x;
    int t = threadIdx.x;
    int v = (i < N_NODES) ? deg[i] : 0;
    s[t] = v;
    __syncthreads();
    for (int off = 1; off < 256; off <<= 1) {
        int u = (t >= off) ? s[t - off] : 0;
        __syncthreads();
        s[t] += u;
        __syncthreads();
    }
    if (i < N_NODES) {
        int ex = base[blockIdx.x] + s[t] - v;
        row_ptr[i] = ex;
        cursor[i]  = ex;
    }
}

// XCD-partitioned fill: class c writes only dst in [c*NPC,(c+1)*NPC)
__global__ void fill_kernel(const int* __restrict__ ei0, const int* __restrict__ ei1,
                            int* __restrict__ cur0, int* __restrict__ cur1,
                            int2* __restrict__ csr0, int2* __restrict__ csr1) {
    const int* ei = blockIdx.y ? ei1 : ei0;
    int* cursor   = blockIdx.y ? cur1 : cur0;
    int2* csr     = blockIdx.y ? csr1 : csr0;
    int chunk = blockIdx.x >> 3;
    int cls   = blockIdx.x & 7;
    int e0 = chunk * FCHUNK;
    int e1 = e0 + FCHUNK; if (e1 > N_EDGES) e1 = N_EDGES;
    int lo = cls * NPC, hi = lo + NPC;
    for (int e = e0 + threadIdx.x; e < e1; e += 256) {
        int dst = __builtin_nontemporal_load(&ei[N_EDGES + e]);
        if (dst >= lo && dst < hi) {
            int src = __builtin_nontemporal_load(&ei[e]);
            int pos = atomicAdd(&cursor[dst], 1);
            csr[pos] = make_int2(src, e);
        }
    }
}

// ------------------------------------------------- edge-attr aggregation (bf16 out)
__global__ void gather_e_kernel(const float* __restrict__ ea0, const float* __restrict__ ea1,
                                const int* __restrict__ rp0, const int* __restrict__ rp1,
                                const int2* __restrict__ csr0, const int2* __restrict__ csr1,
                                unsigned short* __restrict__ agg0,
                                unsigned short* __restrict__ agg1) {
    const float* ea        = blockIdx.y ? ea1 : ea0;
    const int* row_ptr     = blockIdx.y ? rp1 : rp0;
    const int2* csr        = blockIdx.y ? csr1 : csr0;
    unsigned short* agg    = blockIdx.y ? agg1 : agg0;
    int node = blockIdx.x * 32 + (threadIdx.x >> 3);
    if (node >= N_NODES) return;
    int lane = threadIdx.x & 7;
    int start = row_ptr[node], end = row_ptr[node + 1];
    float acc = 0.f;
    int e = start;
    for (; e + 2 <= end; e += 2) {
        int e0 = csr[e].y, e1 = csr[e + 1].y;
        acc += ea[(size_t)e0 * FE + lane] + ea[(size_t)e1 * FE + lane];
    }
    if (e < end) acc += ea[(size_t)csr[e].y * FE + lane];
    agg[(size_t)node * FIN + FX + lane] = f2bf(acc);
}

// --------------------------------- fp32 -> bf16 convert, row-major -> chunk-major [4][N][32]
__global__ void f2bf_kernel(const float* __restrict__ in0, const float* __restrict__ in1,
                            unsigned short* __restrict__ o0, unsigned short* __restrict__ o1) {
    const float* in       = blockIdx.y ? in1 : in0;
    unsigned short* out16 = blockIdx.y ? o1 : o0;
    int i = blockIdx.x * 256 + threadIdx.x;          // over N_NODES*16 (8 elems each)
    if (i >= N_NODES * 16) return;
    int n = i >> 4, g = i & 15;                      // g: 8-col group
    const float4 v0 = *reinterpret_cast<const float4*>(in + (size_t)n * FX + g * 8);
    const float4 v1 = *reinterpret_cast<const float4*>(in + (size_t)n * FX + g * 8 + 4);
    union { unsigned short us[8]; uint4 v; } o;
    o.us[0] = f2bf(v0.x); o.us[1] = f2bf(v0.y); o.us[2] = f2bf(v0.z); o.us[3] = f2bf(v0.w);
    o.us[4] = f2bf(v1.x); o.us[5] = f2bf(v1.y); o.us[6] = f2bf(v1.z); o.us[7] = f2bf(v1.w);
    *reinterpret_cast<uint4*>(&out16[(size_t)(g >> 2) * CSLAB + (size_t)n * 32 + (g & 3) * 8]) = o.v;
}

// --------------------------------------------- weight convert: fp32 -> bf16, K-pad to 160
__global__ void wcvt_kernel(const float* __restrict__ WA, const float* __restrict__ WB,
                            const float* __restrict__ fcW,
                            unsigned short* __restrict__ w16A, unsigned short* __restrict__ w16B,
                            unsigned short* __restrict__ w16fc) {
    const int CONV = 3 * FX * 160;                   // 61440 per branch
    int idx = blockIdx.x * 256 + threadIdx.x;
    if (idx < 2 * CONV) {
        int br = idx / CONV, r = idx % CONV;
        int l = r / (FX * 160), rem = r % (FX * 160);
        int row = rem / 160, k = rem % 160;
        const float* Wsrc = br ? WB : WA;
        float v = (k < FIN) ? Wsrc[((size_t)l * FX + row) * FIN + k] : 0.f;
        (br ? w16B : w16A)[r] = f2bf(v);
    } else {
        int i = idx - 2 * CONV;
        if (i < FX * FX) w16fc[i] = f2bf(fcW[i]);
    }
}

// ------------------------------------------------- sparse gather, XCD-chunked
// class = blockIdx.x & 7 -> XCD (round-robin). class = (branch<<2)|chunk: each XCD's
// 3.2 MB feature slab (chunk-major [node][32]) stays resident in its private L2, so
// every random per-edge read is a full-line local-L2 hit. 4 lanes/node x 16B.
__global__ void gather_kernel(const unsigned short* __restrict__ x0,
                              const unsigned short* __restrict__ x1,
                              const int* __restrict__ rp0, const int* __restrict__ rp1,
                              const int2* __restrict__ csr0, const int2* __restrict__ csr1,
                              unsigned short* __restrict__ agg0,
                              unsigned short* __restrict__ agg1) {
    const int cls = blockIdx.x & 7;
    const int br  = cls >> 2;
    const int ch  = cls & 3;
    const unsigned short* xc = (br ? x1 : x0) + (size_t)ch * CSLAB;
    const int* row_ptr  = br ? rp1 : rp0;
    const int2* csr     = br ? csr1 : csr0;
    unsigned short* agg = br ? agg1 : agg0;

    int node = (blockIdx.x >> 3) * 64 + (threadIdx.x >> 2);
    if (node >= N_NODES) return;
    int lane = threadIdx.x & 3;
    int start = row_ptr[node], end = row_ptr[node + 1];
    float a[8] = {};
    int e = start;
    for (; e + 4 <= end; e += 4) {
        int s0 = csr[e].x, s1 = csr[e + 1].x, s2 = csr[e + 2].x, s3 = csr[e + 3].x;
        uint4 v0 = *reinterpret_cast<const uint4*>(&xc[(size_t)s0 * 32 + lane * 8]);
        uint4 v1 = *reinterpret_cast<const uint4*>(&xc[(size_t)s1 * 32 + lane * 8]);
        uint4 v2 = *reinterpret_cast<const uint4*>(&xc[(size_t)s2 * 32 + lane * 8]);
        uint4 v3 = *reinterpret_cast<const uint4*>(&xc[(size_t)s3 * 32 + lane * 8]);
#pragma unroll
        for (int q = 0; q < 4; ++q) {
            unsigned u0 = (&v0.x)[q], u1 = (&v1.x)[q], u2 = (&v2.x)[q], u3 = (&v3.x)[q];
            a[q * 2]     += __uint_as_float(u0 << 16) + __uint_as_float(u1 << 16)
                          + __uint_as_float(u2 << 16) + __uint_as_float(u3 << 16);
            a[q * 2 + 1] += __uint_as_float(u0 & 0xffff0000u) + __uint_as_float(u1 & 0xffff0000u)
                          + __uint_as_float(u2 & 0xffff0000u) + __uint_as_float(u3 & 0xffff0000u);
        }
    }
    for (; e < end; ++e) {
        uint4 v = *reinterpret_cast<const uint4*>(&xc[(size_t)csr[e].x * 32 + lane * 8]);
#pragma unroll
        for (int q = 0; q < 4; ++q) {
            unsigned u = (&v.x)[q];
            a[q * 2]     += __uint_as_float(u << 16);
            a[q * 2 + 1] += __uint_as_float(u & 0xffff0000u);
        }
    }
    union { unsigned short us[8]; uint4 v; } o;
#pragma unroll
    for (int q = 0; q < 8; ++q) o.us[q] = f2bf(a[q]);
    *reinterpret_cast<uint4*>(&agg[(size_t)node * FIN + ch * 32 + lane * 8]) = o.v;
}

// ------------------------------------------------- MFMA GEMM: out[N,128] = A[N,K]@W16^T + b
// 256 threads = 4 waves; tile M=64, N=128. A staged in LDS from row-major (agg) or
// chunk-major (h16c). Output row-major fp32 or chunk-major bf16.
// Fragment maps (verified m89): A row=l&15, k=(l>>4)*8+j; B col=l&15, same k;
//                               C col=l&15, row=(l>>4)*4+reg.
template <int K, int KSTEPS, int KP, bool LEAKY, bool ACHUNK, bool OCHUNK>
__global__ void mfma_gemm_kernel(const unsigned short* __restrict__ A0,
                                 const unsigned short* __restrict__ A1,
                                 const unsigned short* __restrict__ W0,
                                 const unsigned short* __restrict__ W1,
                                 const float* __restrict__ b0, const float* __restrict__ b1,
                                 void* __restrict__ O0, void* __restrict__ O1) {
    const unsigned short* A   = blockIdx.y ? A1 : A0;
    const unsigned short* W16 = blockIdx.y ? W1 : W0;
    const float* bias         = blockIdx.y ? b1 : b0;
    void* O                   = blockIdx.y ? O1 : O0;

    constexpr int KLDS = KSTEPS * 32;
    __shared__ unsigned short As[64 * KP];

    const int row0 = blockIdx.x * 64;
    if constexpr (ACHUNK) {
        for (int idx = threadIdx.x; idx < 64 * 16; idx += 256) {
            int r = idx >> 4, g = idx & 15;
            *reinterpret_cast<uint4*>(&As[r * KP + g * 8]) =
                *reinterpret_cast<const uint4*>(
                    &A[(size_t)(g >> 2) * CSLAB + (size_t)(row0 + r) * 32 + (g & 3) * 8]);
        }
    } else {
        constexpr int CH = K / 8;                    // 17 for K=136
        constexpr int PADCH = KLDS / 8 - CH;
        for (int idx = threadIdx.x; idx < 64 * CH; idx += 256) {
            int r = idx / CH, c = idx - r * CH;
            *reinterpret_cast<uint4*>(&As[r * KP + c * 8]) =
                *reinterpret_cast<const uint4*>(&A[(size_t)(row0 + r) * K + c * 8]);
        }
        if constexpr (PADCH > 0) {
            const uint4 z = {0u, 0u, 0u, 0u};
            for (int idx = threadIdx.x; idx < 64 * PADCH; idx += 256) {
                int r = idx / PADCH, c = CH + (idx - r * PADCH);
                *reinterpret_cast<uint4*>(&As[r * KP + c * 8]) = z;
            }
        }
    }
    __syncthreads();

    const int wid = threadIdx.x >> 6;
    const int l   = threadIdx.x & 63;
    const int l16 = l & 15, lhi = l >> 4;
    const unsigned short* Arow = &As[(wid * 16 + l16) * KP + lhi * 8];

    float4v acc[8];
#pragma unroll
    for (int f = 0; f < 8; ++f) acc[f] = (float4v){0.f, 0.f, 0.f, 0.f};

#pragma unroll
    for (int ks = 0; ks < KSTEPS; ++ks) {
        short8v a = *reinterpret_cast<const short8v*>(Arow + ks * 32);
#pragma unroll
        for (int f = 0; f < 8; ++f) {
            short8v b = *reinterpret_cast<const short8v*>(
                &W16[(size_t)(f * 16 + l16) * KLDS + ks * 32 + lhi * 8]);
            acc[f] = __builtin_amdgcn_mfma_f32_16x16x32_bf16(a, b, acc[f], 0, 0, 0);
        }
    }

    float bs[8];
#pragma unroll
    for (int f = 0; f < 8; ++f) bs[f] = bias[f * 16 + l16];

#pragma unroll
    for (int f = 0; f < 8; ++f) {
#pragma unroll
        for (int j = 0; j < 4; ++j) {
            int r = row0 + wid * 16 + lhi * 4 + j;
            if (r < N_NODES) {
                float v = acc[f][j] + bs[f];
                if (LEAKY) v = v > 0.f ? v : 0.01f * v;
                if constexpr (OCHUNK) {
                    ((unsigned short*)O)[(size_t)(f >> 1) * CSLAB + (size_t)r * 32 +
                                         (f & 1) * 16 + l16] = f2bf(v);
                } else {
                    ((float*)O)[(size_t)r * FX + f * 16 + l16] = v;
                }
            }
        }
    }
}

// ---------------------------------------------------------------- launch
extern "C" void kernel_launch(void* const* d_in, const int* in_sizes, int n_in,
                              void* d_out, int out_size, void* d_ws, size_t ws_size,
                              hipStream_t stream) {
    const float* x1  = (const float*)d_in[0];
    const int*   ei1 = (const int*)  d_in[1];
    const float* ea1 = (const float*)d_in[2];
    const float* x2  = (const float*)d_in[3];
    const int*   ei2 = (const int*)  d_in[4];
    const float* ea2 = (const float*)d_in[5];
    const float* WA  = (const float*)d_in[6];
    const float* bA  = (const float*)d_in[7];
    const float* WB  = (const float*)d_in[8];
    const float* bB  = (const float*)d_in[9];
    const float* fcW = (const float*)d_in[10];
    const float* fcb = (const float*)d_in[11];
    float* out = (float*)d_out;

    // workspace layout
    unsigned short* agg16a = (unsigned short*)d_ws;          // NPAD*FIN bf16 (row-major)
    unsigned short* agg16b = agg16a + (size_t)NPAD * FIN;
    unsigned short* h16a   = agg16b + (size_t)NPAD * FIN;    // 4 chunk slabs = NPAD*FX bf16
    unsigned short* h16b   = h16a + (size_t)NPAD * FX;
    unsigned short* w16A   = h16b + (size_t)NPAD * FX;       // 3*128*160
    unsigned short* w16B   = w16A + 3 * FX * 160;
    unsigned short* w16fc  = w16B + 3 * FX * 160;            // 128*128
    int2* csr0 = (int2*)(((size_t)(w16fc + FX * FX) + 15) & ~(size_t)15);
    int2* csr1 = csr0 + N_EDGES;
    int* deg0    = (int*)(csr1 + N_EDGES);                   // deg0,deg1 contiguous (one memset)
    int* deg1    = deg0 + N_NODES;
    int* rowp0   = deg1 + N_NODES;
    int* rowp1   = rowp0 + N_NODES + 1;
    int* cur0    = rowp1 + N_NODES + 1;
    int* cur1    = cur0 + N_NODES;
    int* part0   = cur1 + N_NODES;
    int* part1   = part0 + NB_SCAN;
    int* base0   = part1 + NB_SCAN;
    int* base1   = base0 + NB_SCAN;
    size_t needed = (size_t)(base1 + NB_SCAN) - (size_t)d_ws;
    if (ws_size < needed) return;                            // output stays poisoned

    const dim3 b256(256);
    const dim3 gE(6250, 2);                       // edges / 256
    const dim3 gS(NB_SCAN, 2);
    const dim3 g1(1, 2);
    const dim3 gF(NCHUNK * NXCD, 2);              // 6256
    const dim3 gGE(1563, 2);
    const dim3 gG(782 * NXCD);                    // 6256: class in x for XCD binding
    const dim3 gC(3125, 2);                       // N_NODES*16 / 256
    const dim3 gM(782, 2);
    const dim3 gW(544);

    // CSR build, both branches per launch
    hipMemsetAsync(deg0, 0, 2 * N_NODES * sizeof(int), stream);
    hist_kernel<<<gE, b256, 0, stream>>>(ei1, ei2, deg0, deg1);
    scan1_kernel<<<gS, b256, 0, stream>>>(deg0, deg1, part0, part1);
    scan2_kernel<<<g1, b256, 0, stream>>>(part0, part1, base0, base1, rowp0, rowp1);
    scan3_kernel<<<gS, b256, 0, stream>>>(deg0, deg1, base0, base1, rowp0, rowp1, cur0, cur1);
    fill_kernel<<<gF, b256, 0, stream>>>(ei1, ei2, cur0, cur1, csr0, csr1);

    // layer-invariant pieces
    gather_e_kernel<<<gGE, b256, 0, stream>>>(ea1, ea2, rowp0, rowp1, csr0, csr1, agg16a, agg16b);
    f2bf_kernel<<<gC, b256, 0, stream>>>(x1, x2, h16a, h16b);
    wcvt_kernel<<<gW, b256, 0, stream>>>(WA, WB, fcW, w16A, w16B, w16fc);

    // 3 conv layers: gather (chunk-major in, row-major agg out) + MFMA GEMM (chunk-major out)
    for (int l = 0; l < 3; ++l) {
        gather_kernel<<<gG, b256, 0, stream>>>(h16a, h16b, rowp0, rowp1, csr0, csr1,
                                               agg16a, agg16b);
        mfma_gemm_kernel<FIN, 5, 168, true, false, true><<<gM, b256, 0, stream>>>(
            agg16a, agg16b, w16A + (size_t)l * FX * 160, w16B + (size_t)l * FX * 160,
            bA + (size_t)l * FX, bB + (size_t)l * FX, h16a, h16b);
    }
    // final fc: chunk-major A, row-major fp32 out, no activation
    mfma_gemm_kernel<FX, 4, 136, false, true, false><<<gM, b256, 0, stream>>>(
        h16a, h16b, w16fc, w16fc, fcb, fcb, out, out + (size_t)N_NODES * FX);
}